// Round 12
// baseline (140.378 us; speedup 1.0000x reference)
//
#include <hip/hip_runtime.h>
#include <hip/hip_fp16.h>
#include <cstdint>

#define FEAT 64
#define NEG_SLOPE 0.2f
#define PBLK 128          // blocks in coarse binning pass
#define NODE_SH 8         // 256 nodes per bucket
#define CAP 5120          // fixed slab capacity per bucket (mean 4096, sd ~64)

// ---------- zero bucket cursors + the two We·att_e dots, one tiny kernel ----------
__global__ void zero_prep_kernel(int* __restrict__ gcur,
                                 const float* __restrict__ We1, const float* __restrict__ ae1,
                                 const float* __restrict__ We2, const float* __restrict__ ae2,
                                 float* __restrict__ cbuf) {
    int tid = threadIdx.x;
    if (tid < 64) {
        for (int i = tid; i < 256; i += 64) gcur[i] = 0;
    } else if (tid < 192) {
        int lane = tid & 63;
        bool second = tid >= 128;
        const float* a = second ? We2 : We1;
        const float* b = second ? ae2 : ae1;
        float v = a[lane] * b[lane];
        #pragma unroll
        for (int off = 32; off; off >>= 1) v += __shfl_xor(v, off, 64);
        if (lane == 0) cbuf[second ? 1 : 0] = v;
    }
}

// ---------- fused: blocks [0,PBLK) = coarse edge binning; rest = layer-1 GEMM ----------
__global__ __launch_bounds__(256) void coarse_gemm1_kernel(
        // coarse args
        const int* __restrict__ src, const int* __restrict__ dst,
        const float* __restrict__ eattr, int* __restrict__ gcur,
        int2* __restrict__ tmp, int E,
        // gemm args (layer 1, f32 input)
        const float* __restrict__ X, const float* __restrict__ W,
        const float* __restrict__ att_s, const float* __restrict__ att_d,
        __half* __restrict__ Hh, float* __restrict__ a_src,
        float* __restrict__ a_dst, int N) {
    __shared__ float smem[FEAT * FEAT];        // 16KB union
    int tid = threadIdx.x;

    if (blockIdx.x < PBLK) {
        // ===== coarse path =====
        int* lcnt = (int*)smem;
        int* lcur = (int*)smem + 256;
        int p = blockIdx.x;
        lcnt[tid] = 0;
        __syncthreads();
        int ch = (E + PBLK - 1) / PBLK;
        int beg = p * ch, end = min(E, beg + ch);
        for (int e = beg + tid; e < end; e += 256)
            atomicAdd(&lcnt[dst[e] >> NODE_SH], 1);
        __syncthreads();
        int c = lcnt[tid];
        lcur[tid] = c ? atomicAdd(&gcur[tid], c) : 0;   // block's base within bucket slab
        __syncthreads();
        for (int e = beg + tid; e < end; e += 256) {
            int d = dst[e];
            int bkt = d >> NODE_SH;
            int slot = atomicAdd(&lcur[bkt], 1);
            tmp[(size_t)bkt * CAP + slot] =
                make_int2((int)(((unsigned)d << 16) | (unsigned)src[e]),
                          __float_as_int(eattr[e]));
        }
        return;
    }

    // ===== gemm path =====
    int wave = tid >> 6, lane = tid & 63;
    const float4* W4 = (const float4*)W;
    float4* Ws4 = (float4*)smem;
    #pragma unroll
    for (int i = 0; i < 4; ++i) Ws4[tid + i * 256] = W4[tid + i * 256];

    int row0 = (blockIdx.x - PBLK) * 32 + wave * 8;
    float xv[8];
    #pragma unroll
    for (int r = 0; r < 8; ++r) {
        int row = row0 + r;
        xv[r] = (row < N) ? X[(size_t)row * FEAT + lane] : 0.f;
    }
    __syncthreads();

    float acc[8] = {0.f, 0.f, 0.f, 0.f, 0.f, 0.f, 0.f, 0.f};
    #pragma unroll
    for (int k = 0; k < FEAT; ++k) {
        float wk = smem[k * FEAT + lane];
        #pragma unroll
        for (int r = 0; r < 8; ++r) {
            float xk = __uint_as_float(__builtin_amdgcn_readlane(__float_as_uint(xv[r]), k));
            acc[r] = fmaf(xk, wk, acc[r]);
        }
    }

    float as_w = att_s[lane], ad_w = att_d[lane];
    #pragma unroll
    for (int r = 0; r < 8; ++r) {
        int row = row0 + r;
        if (row >= N) break;
        Hh[(size_t)row * FEAT + lane] = __float2half(acc[r]);
        float sv = acc[r] * as_w;
        float dv = acc[r] * ad_w;
        #pragma unroll
        for (int off = 32; off; off >>= 1) {
            sv += __shfl_xor(sv, off, 64);
            dv += __shfl_xor(dv, off, 64);
        }
        if (lane == 0) { a_src[row] = sv; a_dst[row] = dv; }
    }
}

// ---------- fine: per bucket: per-node count+scan -> rowptr2, epack scatter,
//            and degree-sorted node permutation (counting sort, key=min(deg,63))
__global__ __launch_bounds__(256) void fine_kernel(
        const int2* __restrict__ tmp, const int* __restrict__ gcur,
        int2* __restrict__ rowptr2, unsigned* __restrict__ epack,
        int* __restrict__ nodeperm, int N) {
    __shared__ int cnt[256];
    __shared__ int wsum[4];
    __shared__ int hist[64];
    __shared__ int hcur[64];
    int b = blockIdx.x, tid = threadIdx.x;
    int base = b * CAP;
    int cb = gcur[b];                 // edges in this bucket
    cnt[tid] = 0;
    if (tid < 64) hist[tid] = 0;
    __syncthreads();
    for (int i = tid; i < cb; i += 256)
        atomicAdd(&cnt[((unsigned)tmp[base + i].x >> 16) & 255], 1);
    __syncthreads();
    int lane = tid & 63, wave = tid >> 6;
    int deg = cnt[tid];
    int v = deg;
    #pragma unroll
    for (int off = 1; off < 64; off <<= 1) {
        int t = __shfl_up(v, off, 64);
        if (lane >= off) v += t;
    }
    if (lane == 63) wsum[wave] = v;
    __syncthreads();
    int add = 0;
    for (int w = 0; w < wave; ++w) add += wsum[w];
    int excl = base + v + add - deg;          // exclusive prefix within slab
    int node = (b << NODE_SH) + tid;
    rowptr2[node] = make_int2(excl, excl + deg);   // rowptr2 sized NB*256
    int key = min(deg, 63);
    atomicAdd(&hist[key], 1);
    __syncthreads();
    // exclusive scan of hist[64] (wave 0) -> hcur
    if (tid < 64) {
        int h = hist[tid], s = h;
        #pragma unroll
        for (int off = 1; off < 64; off <<= 1) {
            int t = __shfl_up(s, off, 64);
            if (tid >= off) s += t;
        }
        hcur[tid] = s - h;
    }
    cnt[tid] = excl;                  // reuse as per-node scatter cursor
    __syncthreads();
    int sortpos = atomicAdd(&hcur[key], 1);
    nodeperm[(b << NODE_SH) + sortpos] = node;
    for (int i = tid; i < cb; i += 256) {
        int2 t2 = tmp[base + i];
        int d8 = ((unsigned)t2.x >> 16) & 255;
        int pos = atomicAdd(&cnt[d8], 1);
        unsigned packed = ((unsigned)t2.x << 16) |
                          (unsigned)__half_as_ushort(__float2half(__int_as_float(t2.y)));
        epack[pos] = packed;                   // src:16 | fp16(eattr):16
    }
}

// ---------- GEMM (h = x @ W) fused with attention dots; layer 2, fp16 input ----------
__global__ __launch_bounds__(256) void gemm2_att_kernel(
        const __half* __restrict__ Xh, const float* __restrict__ W,
        const float* __restrict__ att_s, const float* __restrict__ att_d,
        __half* __restrict__ Hh, float* __restrict__ a_src,
        float* __restrict__ a_dst, int N) {
    __shared__ float Ws[FEAT * FEAT];
    int tid = threadIdx.x, wave = tid >> 6, lane = tid & 63;

    const float4* W4 = (const float4*)W;
    float4* Ws4 = (float4*)Ws;
    #pragma unroll
    for (int i = 0; i < 4; ++i) Ws4[tid + i * 256] = W4[tid + i * 256];

    int row0 = blockIdx.x * 32 + wave * 8;
    float xv[8];
    #pragma unroll
    for (int r = 0; r < 8; ++r) {
        int row = row0 + r;
        xv[r] = (row < N) ? __half2float(Xh[(size_t)row * FEAT + lane]) : 0.f;
    }
    __syncthreads();

    float acc[8] = {0.f, 0.f, 0.f, 0.f, 0.f, 0.f, 0.f, 0.f};
    #pragma unroll
    for (int k = 0; k < FEAT; ++k) {
        float wk = Ws[k * FEAT + lane];
        #pragma unroll
        for (int r = 0; r < 8; ++r) {
            float xk = __uint_as_float(__builtin_amdgcn_readlane(__float_as_uint(xv[r]), k));
            acc[r] = fmaf(xk, wk, acc[r]);
        }
    }

    float as_w = att_s[lane], ad_w = att_d[lane];
    #pragma unroll
    for (int r = 0; r < 8; ++r) {
        int row = row0 + r;
        if (row >= N) break;
        Hh[(size_t)row * FEAT + lane] = __float2half(acc[r]);
        float sv = acc[r] * as_w;
        float dv = acc[r] * ad_w;
        #pragma unroll
        for (int off = 32; off; off >>= 1) {
            sv += __shfl_xor(sv, off, 64);
            dv += __shfl_xor(dv, off, 64);
        }
        if (lane == 0) { a_src[row] = sv; a_dst[row] = dv; }
    }
}

// ---------- fused per-node softmax + aggregate (degree-sorted schedule) ----------
// 16-lane group = node (via nodeperm). Second 8-gather half skipped when the
// wave's max remaining count <= 8 (coherent thanks to degree sorting).
template <bool FINAL>
__global__ __launch_bounds__(256) void fused_agg_kernel(
        const int2* __restrict__ rowptr2, const unsigned* __restrict__ epack,
        const int* __restrict__ nodeperm,
        const float* __restrict__ a_src, const float* __restrict__ a_dst,
        const float* __restrict__ cptr, const uint2* __restrict__ Hh2,
        const float* __restrict__ bias, void* __restrict__ OUTv, int N) {
    int tid = threadIdx.x;
    int wave = tid >> 6, lane = tid & 63;
    int grp = lane >> 4, gl = lane & 15;
    int grpBase = grp << 4;
    int slot = blockIdx.x * 16 + wave * 4 + grp;
    int node = nodeperm[slot];
    int2 be = rowptr2[node];
    int beg = be.x, end = be.y;
    bool valid = node < N;
    float c = *cptr;
    float adn = valid ? a_dst[node] : 0.f;

    float den = 0.f;
    float4 a0 = {0,0,0,0}, a1 = {0,0,0,0}, a2 = {0,0,0,0}, a3 = {0,0,0,0};

    int nchunk = (end - beg + 15) >> 4;
    int wc = nchunk;
    wc = max(wc, __shfl_xor(wc, 16, 64));
    wc = max(wc, __shfl_xor(wc, 32, 64));

    for (int ch = 0; ch < wc; ++ch) {
        int j = beg + ch * 16 + gl;
        int s = 0;
        float w = 0.f;
        if (j < end) {
            unsigned ep = epack[j];
            s = (int)(ep >> 16);
            float ea = __half2float(__ushort_as_half((unsigned short)(ep & 0xffffu)));
            float l = fmaf(c, ea, a_src[s] + adn);
            l = (l > 0.f) ? l : NEG_SLOPE * l;
            w = __expf(l);
        }
        den += w;   // per-lane partial; reduced once after the loop

        // wave-max remaining count (coherent after degree sort)
        int rem = end - (beg + ch * 16);
        rem = min(max(rem, 0), 16);
        int mrem = rem;
        mrem = max(mrem, __shfl_xor(mrem, 16, 64));
        mrem = max(mrem, __shfl_xor(mrem, 32, 64));

        #pragma unroll
        for (int half = 0; half < 2; ++half) {
            if (half == 1 && mrem <= 8) break;
            int kb = grpBase + half * 8;
            int   s0 = __shfl(s, kb + 0, 64), s1 = __shfl(s, kb + 1, 64);
            int   s2 = __shfl(s, kb + 2, 64), s3 = __shfl(s, kb + 3, 64);
            int   s4 = __shfl(s, kb + 4, 64), s5 = __shfl(s, kb + 5, 64);
            int   s6 = __shfl(s, kb + 6, 64), s7 = __shfl(s, kb + 7, 64);
            float w0 = __shfl(w, kb + 0, 64), w1 = __shfl(w, kb + 1, 64);
            float w2 = __shfl(w, kb + 2, 64), w3 = __shfl(w, kb + 3, 64);
            float w4 = __shfl(w, kb + 4, 64), w5 = __shfl(w, kb + 5, 64);
            float w6 = __shfl(w, kb + 6, 64), w7 = __shfl(w, kb + 7, 64);
            uint2 u0 = Hh2[(size_t)s0 * 16 + gl];
            uint2 u1 = Hh2[(size_t)s1 * 16 + gl];
            uint2 u2 = Hh2[(size_t)s2 * 16 + gl];
            uint2 u3 = Hh2[(size_t)s3 * 16 + gl];
            uint2 u4 = Hh2[(size_t)s4 * 16 + gl];
            uint2 u5 = Hh2[(size_t)s5 * 16 + gl];
            uint2 u6 = Hh2[(size_t)s6 * 16 + gl];
            uint2 u7 = Hh2[(size_t)s7 * 16 + gl];
            float2 f00 = __half22float2(*(__half2*)&u0.x), f01 = __half22float2(*(__half2*)&u0.y);
            float2 f10 = __half22float2(*(__half2*)&u1.x), f11 = __half22float2(*(__half2*)&u1.y);
            float2 f20 = __half22float2(*(__half2*)&u2.x), f21 = __half22float2(*(__half2*)&u2.y);
            float2 f30 = __half22float2(*(__half2*)&u3.x), f31 = __half22float2(*(__half2*)&u3.y);
            float2 f40 = __half22float2(*(__half2*)&u4.x), f41 = __half22float2(*(__half2*)&u4.y);
            float2 f50 = __half22float2(*(__half2*)&u5.x), f51 = __half22float2(*(__half2*)&u5.y);
            float2 f60 = __half22float2(*(__half2*)&u6.x), f61 = __half22float2(*(__half2*)&u6.y);
            float2 f70 = __half22float2(*(__half2*)&u7.x), f71 = __half22float2(*(__half2*)&u7.y);
            a0.x = fmaf(w0, f00.x, a0.x); a0.y = fmaf(w0, f00.y, a0.y);
            a0.z = fmaf(w0, f01.x, a0.z); a0.w = fmaf(w0, f01.y, a0.w);
            a1.x = fmaf(w1, f10.x, a1.x); a1.y = fmaf(w1, f10.y, a1.y);
            a1.z = fmaf(w1, f11.x, a1.z); a1.w = fmaf(w1, f11.y, a1.w);
            a2.x = fmaf(w2, f20.x, a2.x); a2.y = fmaf(w2, f20.y, a2.y);
            a2.z = fmaf(w2, f21.x, a2.z); a2.w = fmaf(w2, f21.y, a2.w);
            a3.x = fmaf(w3, f30.x, a3.x); a3.y = fmaf(w3, f30.y, a3.y);
            a3.z = fmaf(w3, f31.x, a3.z); a3.w = fmaf(w3, f31.y, a3.w);
            a0.x = fmaf(w4, f40.x, a0.x); a0.y = fmaf(w4, f40.y, a0.y);
            a0.z = fmaf(w4, f41.x, a0.z); a0.w = fmaf(w4, f41.y, a0.w);
            a1.x = fmaf(w5, f50.x, a1.x); a1.y = fmaf(w5, f50.y, a1.y);
            a1.z = fmaf(w5, f51.x, a1.z); a1.w = fmaf(w5, f51.y, a1.w);
            a2.x = fmaf(w6, f60.x, a2.x); a2.y = fmaf(w6, f60.y, a2.y);
            a2.z = fmaf(w6, f61.x, a2.z); a2.w = fmaf(w6, f61.y, a2.w);
            a3.x = fmaf(w7, f70.x, a3.x); a3.y = fmaf(w7, f70.y, a3.y);
            a3.z = fmaf(w7, f71.x, a3.z); a3.w = fmaf(w7, f71.y, a3.w);
        }
    }

    // den reduce across the 16-lane group
    den += __shfl_xor(den, 1, 64);
    den += __shfl_xor(den, 2, 64);
    den += __shfl_xor(den, 4, 64);
    den += __shfl_xor(den, 8, 64);

    if (valid) {
        float4 b4 = ((const float4*)bias)[gl];
        float inv = 1.f / (den + 1e-16f);
        float ox = (a0.x + a1.x + a2.x + a3.x) * inv + b4.x;
        float oy = (a0.y + a1.y + a2.y + a3.y) * inv + b4.y;
        float oz = (a0.z + a1.z + a2.z + a3.z) * inv + b4.z;
        float ow = (a0.w + a1.w + a2.w + a3.w) * inv + b4.w;
        if constexpr (FINAL) {
            ((float4*)OUTv)[(size_t)node * 16 + gl] = make_float4(ox, oy, oz, ow);
        } else {
            __half2 h01 = __floats2half2_rn(fmaxf(ox, 0.f), fmaxf(oy, 0.f));
            __half2 h23 = __floats2half2_rn(fmaxf(oz, 0.f), fmaxf(ow, 0.f));
            uint2 u;
            u.x = *(unsigned*)&h01;
            u.y = *(unsigned*)&h23;
            ((uint2*)OUTv)[(size_t)node * 16 + gl] = u;
        }
    }
}

// ---------- host ----------

static inline size_t align256(size_t x) { return (x + 255) & ~size_t(255); }

extern "C" void kernel_launch(void* const* d_in, const int* in_sizes, int n_in,
                              void* d_out, int out_size, void* d_ws, size_t ws_size,
                              hipStream_t stream) {
    const float* x        = (const float*)d_in[0];
    const int*   eidx     = (const int*)d_in[1];
    const float* eattr    = (const float*)d_in[2];
    const float* W1       = (const float*)d_in[3];
    const float* att_s1   = (const float*)d_in[4];
    const float* att_d1   = (const float*)d_in[5];
    const float* We1      = (const float*)d_in[6];
    const float* att_e1   = (const float*)d_in[7];
    const float* b1       = (const float*)d_in[8];
    const float* W2       = (const float*)d_in[9];
    const float* att_s2   = (const float*)d_in[10];
    const float* att_d2   = (const float*)d_in[11];
    const float* We2      = (const float*)d_in[12];
    const float* att_e2   = (const float*)d_in[13];
    const float* b2       = (const float*)d_in[14];
    float* OUT = (float*)d_out;

    const int N = in_sizes[0] / FEAT;
    const int E = in_sizes[2];
    const int* src = eidx;
    const int* dst = eidx + E;
    const int NB = (N + (1 << NODE_SH) - 1) >> NODE_SH;   // 196 node-buckets
    const int NPAD = NB << NODE_SH;                        // padded node count

    char* ws = (char*)d_ws;
    size_t off = 0;
    __half* Hh     = (__half*)(ws + off); off = align256(off + (size_t)N * FEAT * 2);
    __half* out1h  = (__half*)(ws + off); off = align256(off + (size_t)N * FEAT * 2);
    float* a_src   = (float*)(ws + off); off = align256(off + (size_t)N * 4);
    float* a_dst   = (float*)(ws + off); off = align256(off + (size_t)N * 4);
    int2*  rowptr2 = (int2*)(ws + off); off = align256(off + (size_t)NPAD * 8);
    int*   nodeperm= (int*)(ws + off); off = align256(off + (size_t)NPAD * 4);
    int2*  tmp     = (int2*)(ws + off); off = align256(off + (size_t)NB * CAP * 8);
    unsigned* epack= (unsigned*)(ws + off); off = align256(off + (size_t)NB * CAP * 4);
    int*   gcur    = (int*)(ws + off); off = align256(off + 256 * 4);
    float* cbuf    = (float*)(ws + off); off = align256(off + 2 * 4);
    (void)ws_size;

    const int gemmBlocks = (N + 31) / 32;
    const int aggBlocks  = NPAD / 16;

    // ===== prep =====
    zero_prep_kernel<<<1, 256, 0, stream>>>(gcur, We1, att_e1, We2, att_e2, cbuf);

    // ===== coarse binning || layer-1 GEMM (independent, co-dispatched) =====
    coarse_gemm1_kernel<<<PBLK + gemmBlocks, 256, 0, stream>>>(
        src, dst, eattr, gcur, tmp, E,
        x, W1, att_s1, att_d1, Hh, a_src, a_dst, N);

    // ===== fine pass: per-node grouping + rowptr2 + degree-sorted nodeperm =====
    fine_kernel<<<NB, 256, 0, stream>>>(tmp, gcur, rowptr2, epack, nodeperm, N);

    // ===== layer 1 aggregate (fp16 out, bias+ReLU fused) =====
    fused_agg_kernel<false><<<aggBlocks, 256, 0, stream>>>(rowptr2, epack, nodeperm,
                                                           a_src, a_dst, cbuf + 0,
                                                           (const uint2*)Hh, b1, out1h, N);

    // ===== layer 2 =====
    gemm2_att_kernel<<<gemmBlocks, 256, 0, stream>>>(out1h, W2, att_s2, att_d2,
                                                     Hh, a_src, a_dst, N);
    fused_agg_kernel<true><<<aggBlocks, 256, 0, stream>>>(rowptr2, epack, nodeperm,
                                                          a_src, a_dst, cbuf + 1,
                                                          (const uint2*)Hh, b2, OUT, N);
}

// Round 13
// 133.892 us; speedup vs baseline: 1.0484x; 1.0484x over previous
//
#include <hip/hip_runtime.h>
#include <hip/hip_fp16.h>
#include <cstdint>

#define FEAT 64
#define NEG_SLOPE 0.2f
#define PBLK 128          // blocks in coarse binning pass
#define NODE_SH 8         // 256 nodes per bucket
#define CAP 5120          // fixed slab capacity per bucket (mean 4096, sd ~64)

// ---------- zero bucket cursors + the two We·att_e dots, one tiny kernel ----------
__global__ void zero_prep_kernel(int* __restrict__ gcur,
                                 const float* __restrict__ We1, const float* __restrict__ ae1,
                                 const float* __restrict__ We2, const float* __restrict__ ae2,
                                 float* __restrict__ cbuf) {
    int tid = threadIdx.x;
    if (tid < 64) {
        for (int i = tid; i < 256; i += 64) gcur[i] = 0;
    } else if (tid < 192) {
        int lane = tid & 63;
        bool second = tid >= 128;
        const float* a = second ? We2 : We1;
        const float* b = second ? ae2 : ae1;
        float v = a[lane] * b[lane];
        #pragma unroll
        for (int off = 32; off; off >>= 1) v += __shfl_xor(v, off, 64);
        if (lane == 0) cbuf[second ? 1 : 0] = v;
    }
}

// ---------- fused: blocks [0,PBLK) = coarse edge binning; rest = layer-1 GEMM ----------
// Independent work co-dispatched so the scattered-atomic coarse pass hides
// under the dense-VALU gemm pass.
__global__ __launch_bounds__(256) void coarse_gemm1_kernel(
        // coarse args
        const int* __restrict__ src, const int* __restrict__ dst,
        const float* __restrict__ eattr, int* __restrict__ gcur,
        int2* __restrict__ tmp, int E,
        // gemm args (layer 1, f32 input)
        const float* __restrict__ X, const float* __restrict__ W,
        const float* __restrict__ att_s, const float* __restrict__ att_d,
        __half* __restrict__ Hh, float* __restrict__ a_src,
        float* __restrict__ a_dst, int N) {
    __shared__ float smem[FEAT * FEAT];        // 16KB union
    int tid = threadIdx.x;

    if (blockIdx.x < PBLK) {
        // ===== coarse path =====
        int* lcnt = (int*)smem;
        int* lcur = (int*)smem + 256;
        int p = blockIdx.x;
        lcnt[tid] = 0;
        __syncthreads();
        int ch = (E + PBLK - 1) / PBLK;
        int beg = p * ch, end = min(E, beg + ch);
        for (int e = beg + tid; e < end; e += 256)
            atomicAdd(&lcnt[dst[e] >> NODE_SH], 1);
        __syncthreads();
        int c = lcnt[tid];
        lcur[tid] = c ? atomicAdd(&gcur[tid], c) : 0;   // block's base within bucket slab
        __syncthreads();
        for (int e = beg + tid; e < end; e += 256) {
            int d = dst[e];
            int bkt = d >> NODE_SH;
            int slot = atomicAdd(&lcur[bkt], 1);
            tmp[(size_t)bkt * CAP + slot] =
                make_int2((int)(((unsigned)d << 16) | (unsigned)src[e]),
                          __float_as_int(eattr[e]));
        }
        return;
    }

    // ===== gemm path =====
    int wave = tid >> 6, lane = tid & 63;
    const float4* W4 = (const float4*)W;
    float4* Ws4 = (float4*)smem;
    #pragma unroll
    for (int i = 0; i < 4; ++i) Ws4[tid + i * 256] = W4[tid + i * 256];

    int row0 = (blockIdx.x - PBLK) * 32 + wave * 8;
    float xv[8];
    #pragma unroll
    for (int r = 0; r < 8; ++r) {
        int row = row0 + r;
        xv[r] = (row < N) ? X[(size_t)row * FEAT + lane] : 0.f;
    }
    __syncthreads();

    float acc[8] = {0.f, 0.f, 0.f, 0.f, 0.f, 0.f, 0.f, 0.f};
    #pragma unroll
    for (int k = 0; k < FEAT; ++k) {
        float wk = smem[k * FEAT + lane];
        #pragma unroll
        for (int r = 0; r < 8; ++r) {
            float xk = __uint_as_float(__builtin_amdgcn_readlane(__float_as_uint(xv[r]), k));
            acc[r] = fmaf(xk, wk, acc[r]);
        }
    }

    float as_w = att_s[lane], ad_w = att_d[lane];
    #pragma unroll
    for (int r = 0; r < 8; ++r) {
        int row = row0 + r;
        if (row >= N) break;
        Hh[(size_t)row * FEAT + lane] = __float2half(acc[r]);
        float sv = acc[r] * as_w;
        float dv = acc[r] * ad_w;
        #pragma unroll
        for (int off = 32; off; off >>= 1) {
            sv += __shfl_xor(sv, off, 64);
            dv += __shfl_xor(dv, off, 64);
        }
        if (lane == 0) { a_src[row] = sv; a_dst[row] = dv; }
    }
}

// ---------- fine: per bucket, per-node count+scan -> rowptr2 (beg,end) + epack ----------
__global__ __launch_bounds__(256) void fine_kernel(
        const int2* __restrict__ tmp, const int* __restrict__ gcur,
        int2* __restrict__ rowptr2, unsigned* __restrict__ epack, int N) {
    __shared__ int cnt[256];
    __shared__ int wsum[4];
    int b = blockIdx.x, tid = threadIdx.x;
    int base = b * CAP;
    int cb = gcur[b];                 // edges in this bucket
    cnt[tid] = 0;
    __syncthreads();
    for (int i = tid; i < cb; i += 256)
        atomicAdd(&cnt[((unsigned)tmp[base + i].x >> 16) & 255], 1);
    __syncthreads();
    int lane = tid & 63, wave = tid >> 6;
    int v = cnt[tid], orig = v;
    #pragma unroll
    for (int off = 1; off < 64; off <<= 1) {
        int t = __shfl_up(v, off, 64);
        if (lane >= off) v += t;
    }
    if (lane == 63) wsum[wave] = v;
    __syncthreads();
    int add = 0;
    for (int w = 0; w < wave; ++w) add += wsum[w];
    int excl = base + v + add - orig;          // exclusive prefix within slab
    int node = (b << NODE_SH) + tid;
    if (node < N) rowptr2[node] = make_int2(excl, excl + orig);
    __syncthreads();
    cnt[tid] = excl;
    __syncthreads();
    for (int i = tid; i < cb; i += 256) {
        int2 t2 = tmp[base + i];
        int d8 = ((unsigned)t2.x >> 16) & 255;
        int pos = atomicAdd(&cnt[d8], 1);
        unsigned packed = ((unsigned)t2.x << 16) |
                          (unsigned)__half_as_ushort(__float2half(__int_as_float(t2.y)));
        epack[pos] = packed;                   // src:16 | fp16(eattr):16
    }
}

// ---------- GEMM (h = x @ W) fused with attention dots; layer 2, fp16 input ----------
__global__ __launch_bounds__(256) void gemm2_att_kernel(
        const __half* __restrict__ Xh, const float* __restrict__ W,
        const float* __restrict__ att_s, const float* __restrict__ att_d,
        __half* __restrict__ Hh, float* __restrict__ a_src,
        float* __restrict__ a_dst, int N) {
    __shared__ float Ws[FEAT * FEAT];
    int tid = threadIdx.x, wave = tid >> 6, lane = tid & 63;

    const float4* W4 = (const float4*)W;
    float4* Ws4 = (float4*)Ws;
    #pragma unroll
    for (int i = 0; i < 4; ++i) Ws4[tid + i * 256] = W4[tid + i * 256];

    int row0 = blockIdx.x * 32 + wave * 8;
    float xv[8];
    #pragma unroll
    for (int r = 0; r < 8; ++r) {
        int row = row0 + r;
        xv[r] = (row < N) ? __half2float(Xh[(size_t)row * FEAT + lane]) : 0.f;
    }
    __syncthreads();

    float acc[8] = {0.f, 0.f, 0.f, 0.f, 0.f, 0.f, 0.f, 0.f};
    #pragma unroll
    for (int k = 0; k < FEAT; ++k) {
        float wk = Ws[k * FEAT + lane];
        #pragma unroll
        for (int r = 0; r < 8; ++r) {
            float xk = __uint_as_float(__builtin_amdgcn_readlane(__float_as_uint(xv[r]), k));
            acc[r] = fmaf(xk, wk, acc[r]);
        }
    }

    float as_w = att_s[lane], ad_w = att_d[lane];
    #pragma unroll
    for (int r = 0; r < 8; ++r) {
        int row = row0 + r;
        if (row >= N) break;
        Hh[(size_t)row * FEAT + lane] = __float2half(acc[r]);
        float sv = acc[r] * as_w;
        float dv = acc[r] * ad_w;
        #pragma unroll
        for (int off = 32; off; off >>= 1) {
            sv += __shfl_xor(sv, off, 64);
            dv += __shfl_xor(dv, off, 64);
        }
        if (lane == 0) { a_src[row] = sv; a_dst[row] = dv; }
    }
}

// ---------- fused per-node softmax + aggregate ----------
// 16-lane group = node. No max-subtraction (logits bounded, exp safe in f32).
// FINAL=false: write fp16 with bias+ReLU fused (feeds layer-2 gemm).
// FINAL=true : write f32 with bias (network output).
template <bool FINAL>
__global__ __launch_bounds__(256) void fused_agg_kernel(
        const int2* __restrict__ rowptr2, const unsigned* __restrict__ epack,
        const float* __restrict__ a_src, const float* __restrict__ a_dst,
        const float* __restrict__ cptr, const uint2* __restrict__ Hh2,
        const float* __restrict__ bias, void* __restrict__ OUTv, int N) {
    int tid = threadIdx.x;
    int wave = tid >> 6, lane = tid & 63;
    int grp = lane >> 4, gl = lane & 15;
    int grpBase = grp << 4;
    int node = blockIdx.x * 16 + wave * 4 + grp;
    bool valid = node < N;
    int2 be = valid ? rowptr2[node] : make_int2(0, 0);
    int beg = be.x, end = be.y;
    float c = *cptr;
    float adn = valid ? a_dst[node] : 0.f;

    float den = 0.f;
    float4 a0 = {0,0,0,0}, a1 = {0,0,0,0}, a2 = {0,0,0,0}, a3 = {0,0,0,0};

    int nchunk = (end - beg + 15) >> 4;
    int wc = nchunk;
    wc = max(wc, __shfl_xor(wc, 16, 64));
    wc = max(wc, __shfl_xor(wc, 32, 64));

    for (int ch = 0; ch < wc; ++ch) {
        int j = beg + ch * 16 + gl;
        int s = 0;
        float w = 0.f;
        if (j < end) {
            unsigned ep = epack[j];
            s = (int)(ep >> 16);
            float ea = __half2float(__ushort_as_half((unsigned short)(ep & 0xffffu)));
            float l = fmaf(c, ea, a_src[s] + adn);
            l = (l > 0.f) ? l : NEG_SLOPE * l;
            w = __expf(l);
        }
        den += w;   // per-lane partial; reduced once after the loop

        #pragma unroll
        for (int half = 0; half < 2; ++half) {
            int kb = grpBase + half * 8;
            int   s0 = __shfl(s, kb + 0, 64), s1 = __shfl(s, kb + 1, 64);
            int   s2 = __shfl(s, kb + 2, 64), s3 = __shfl(s, kb + 3, 64);
            int   s4 = __shfl(s, kb + 4, 64), s5 = __shfl(s, kb + 5, 64);
            int   s6 = __shfl(s, kb + 6, 64), s7 = __shfl(s, kb + 7, 64);
            float w0 = __shfl(w, kb + 0, 64), w1 = __shfl(w, kb + 1, 64);
            float w2 = __shfl(w, kb + 2, 64), w3 = __shfl(w, kb + 3, 64);
            float w4 = __shfl(w, kb + 4, 64), w5 = __shfl(w, kb + 5, 64);
            float w6 = __shfl(w, kb + 6, 64), w7 = __shfl(w, kb + 7, 64);
            uint2 u0 = Hh2[(size_t)s0 * 16 + gl];
            uint2 u1 = Hh2[(size_t)s1 * 16 + gl];
            uint2 u2 = Hh2[(size_t)s2 * 16 + gl];
            uint2 u3 = Hh2[(size_t)s3 * 16 + gl];
            uint2 u4 = Hh2[(size_t)s4 * 16 + gl];
            uint2 u5 = Hh2[(size_t)s5 * 16 + gl];
            uint2 u6 = Hh2[(size_t)s6 * 16 + gl];
            uint2 u7 = Hh2[(size_t)s7 * 16 + gl];
            float2 f00 = __half22float2(*(__half2*)&u0.x), f01 = __half22float2(*(__half2*)&u0.y);
            float2 f10 = __half22float2(*(__half2*)&u1.x), f11 = __half22float2(*(__half2*)&u1.y);
            float2 f20 = __half22float2(*(__half2*)&u2.x), f21 = __half22float2(*(__half2*)&u2.y);
            float2 f30 = __half22float2(*(__half2*)&u3.x), f31 = __half22float2(*(__half2*)&u3.y);
            float2 f40 = __half22float2(*(__half2*)&u4.x), f41 = __half22float2(*(__half2*)&u4.y);
            float2 f50 = __half22float2(*(__half2*)&u5.x), f51 = __half22float2(*(__half2*)&u5.y);
            float2 f60 = __half22float2(*(__half2*)&u6.x), f61 = __half22float2(*(__half2*)&u6.y);
            float2 f70 = __half22float2(*(__half2*)&u7.x), f71 = __half22float2(*(__half2*)&u7.y);
            a0.x = fmaf(w0, f00.x, a0.x); a0.y = fmaf(w0, f00.y, a0.y);
            a0.z = fmaf(w0, f01.x, a0.z); a0.w = fmaf(w0, f01.y, a0.w);
            a1.x = fmaf(w1, f10.x, a1.x); a1.y = fmaf(w1, f10.y, a1.y);
            a1.z = fmaf(w1, f11.x, a1.z); a1.w = fmaf(w1, f11.y, a1.w);
            a2.x = fmaf(w2, f20.x, a2.x); a2.y = fmaf(w2, f20.y, a2.y);
            a2.z = fmaf(w2, f21.x, a2.z); a2.w = fmaf(w2, f21.y, a2.w);
            a3.x = fmaf(w3, f30.x, a3.x); a3.y = fmaf(w3, f30.y, a3.y);
            a3.z = fmaf(w3, f31.x, a3.z); a3.w = fmaf(w3, f31.y, a3.w);
            a0.x = fmaf(w4, f40.x, a0.x); a0.y = fmaf(w4, f40.y, a0.y);
            a0.z = fmaf(w4, f41.x, a0.z); a0.w = fmaf(w4, f41.y, a0.w);
            a1.x = fmaf(w5, f50.x, a1.x); a1.y = fmaf(w5, f50.y, a1.y);
            a1.z = fmaf(w5, f51.x, a1.z); a1.w = fmaf(w5, f51.y, a1.w);
            a2.x = fmaf(w6, f60.x, a2.x); a2.y = fmaf(w6, f60.y, a2.y);
            a2.z = fmaf(w6, f61.x, a2.z); a2.w = fmaf(w6, f61.y, a2.w);
            a3.x = fmaf(w7, f70.x, a3.x); a3.y = fmaf(w7, f70.y, a3.y);
            a3.z = fmaf(w7, f71.x, a3.z); a3.w = fmaf(w7, f71.y, a3.w);
        }
    }

    // den reduce across the 16-lane group
    den += __shfl_xor(den, 1, 64);
    den += __shfl_xor(den, 2, 64);
    den += __shfl_xor(den, 4, 64);
    den += __shfl_xor(den, 8, 64);

    if (valid) {
        float4 b4 = ((const float4*)bias)[gl];
        float inv = 1.f / (den + 1e-16f);
        float ox = (a0.x + a1.x + a2.x + a3.x) * inv + b4.x;
        float oy = (a0.y + a1.y + a2.y + a3.y) * inv + b4.y;
        float oz = (a0.z + a1.z + a2.z + a3.z) * inv + b4.z;
        float ow = (a0.w + a1.w + a2.w + a3.w) * inv + b4.w;
        if constexpr (FINAL) {
            ((float4*)OUTv)[(size_t)node * 16 + gl] = make_float4(ox, oy, oz, ow);
        } else {
            __half2 h01 = __floats2half2_rn(fmaxf(ox, 0.f), fmaxf(oy, 0.f));
            __half2 h23 = __floats2half2_rn(fmaxf(oz, 0.f), fmaxf(ow, 0.f));
            uint2 u;
            u.x = *(unsigned*)&h01;
            u.y = *(unsigned*)&h23;
            ((uint2*)OUTv)[(size_t)node * 16 + gl] = u;
        }
    }
}

// ---------- host ----------

static inline size_t align256(size_t x) { return (x + 255) & ~size_t(255); }

extern "C" void kernel_launch(void* const* d_in, const int* in_sizes, int n_in,
                              void* d_out, int out_size, void* d_ws, size_t ws_size,
                              hipStream_t stream) {
    const float* x        = (const float*)d_in[0];
    const int*   eidx     = (const int*)d_in[1];
    const float* eattr    = (const float*)d_in[2];
    const float* W1       = (const float*)d_in[3];
    const float* att_s1   = (const float*)d_in[4];
    const float* att_d1   = (const float*)d_in[5];
    const float* We1      = (const float*)d_in[6];
    const float* att_e1   = (const float*)d_in[7];
    const float* b1       = (const float*)d_in[8];
    const float* W2       = (const float*)d_in[9];
    const float* att_s2   = (const float*)d_in[10];
    const float* att_d2   = (const float*)d_in[11];
    const float* We2      = (const float*)d_in[12];
    const float* att_e2   = (const float*)d_in[13];
    const float* b2       = (const float*)d_in[14];
    float* OUT = (float*)d_out;

    const int N = in_sizes[0] / FEAT;
    const int E = in_sizes[2];
    const int* src = eidx;
    const int* dst = eidx + E;
    const int NB = (N + (1 << NODE_SH) - 1) >> NODE_SH;   // 196 node-buckets

    char* ws = (char*)d_ws;
    size_t off = 0;
    __half* Hh     = (__half*)(ws + off); off = align256(off + (size_t)N * FEAT * 2);
    __half* out1h  = (__half*)(ws + off); off = align256(off + (size_t)N * FEAT * 2);
    float* a_src   = (float*)(ws + off); off = align256(off + (size_t)N * 4);
    float* a_dst   = (float*)(ws + off); off = align256(off + (size_t)N * 4);
    int2*  rowptr2 = (int2*)(ws + off); off = align256(off + (size_t)N * 8);
    int2*  tmp     = (int2*)(ws + off); off = align256(off + (size_t)NB * CAP * 8);
    unsigned* epack= (unsigned*)(ws + off); off = align256(off + (size_t)NB * CAP * 4);
    int*   gcur    = (int*)(ws + off); off = align256(off + 256 * 4);
    float* cbuf    = (float*)(ws + off); off = align256(off + 2 * 4);
    (void)ws_size;

    const int gemmBlocks = (N + 31) / 32;
    const int aggBlocks  = (N + 15) / 16;

    // ===== prep =====
    zero_prep_kernel<<<1, 256, 0, stream>>>(gcur, We1, att_e1, We2, att_e2, cbuf);

    // ===== coarse binning || layer-1 GEMM (independent, co-dispatched) =====
    coarse_gemm1_kernel<<<PBLK + gemmBlocks, 256, 0, stream>>>(
        src, dst, eattr, gcur, tmp, E,
        x, W1, att_s1, att_d1, Hh, a_src, a_dst, N);

    // ===== fine pass: per-node grouping + rowptr2 =====
    fine_kernel<<<NB, 256, 0, stream>>>(tmp, gcur, rowptr2, epack, N);

    // ===== layer 1 aggregate (fp16 out, bias+ReLU fused) =====
    fused_agg_kernel<false><<<aggBlocks, 256, 0, stream>>>(rowptr2, epack, a_src, a_dst,
                                                           cbuf + 0, (const uint2*)Hh, b1,
                                                           out1h, N);

    // ===== layer 2 =====
    gemm2_att_kernel<<<gemmBlocks, 256, 0, stream>>>(out1h, W2, att_s2, att_d2,
                                                     Hh, a_src, a_dst, N);
    fused_agg_kernel<true><<<aggBlocks, 256, 0, stream>>>(rowptr2, epack, a_src, a_dst,
                                                          cbuf + 1, (const uint2*)Hh, b2,
                                                          OUT, N);
}